// Round 2
// baseline (258.840 us; speedup 1.0000x reference)
//
#include <hip/hip_runtime.h>

// Problem dims
#define B_   16
#define C_   256
#define HW_  3136      // 56*56
#define W_   56
#define CR_  128
#define KKG_ 144
#define G_   16
#define NPOS (B_*HW_)  // 50176
#define NR   50176     // total rows = B*HW
#define EPS_ 1e-5f

typedef float f32x4 __attribute__((ext_vector_type(4)));
typedef short s16x8 __attribute__((ext_vector_type(8)));
typedef short s16x4 __attribute__((ext_vector_type(4)));

// ws layout (bytes):
//   xT   : [NR][256] bf16              = 25,690,112
//   t_pm : [NR][128] bf16              = 12,845,056
//   kern : [B][144][HW] bf16           = 14,450,688
//   stats: 512 floats (sum|sumsq|scale|shift)
#define XT_OFF_B   0
#define TPM_OFF_B  25690112
#define KERN_OFF_B 38535168
#define STAT_OFF_B 52985856

__device__ inline unsigned short f2bf(float f) {
    unsigned u = __float_as_uint(f);
    u += 0x7fff + ((u >> 16) & 1);          // RNE
    return (unsigned short)(u >> 16);
}
__device__ inline float bf2f(unsigned short h) {
    return __uint_as_float(((unsigned)h) << 16);
}
__device__ inline s16x8 pack8(float4 a, float4 b) {
    s16x8 r;
    r[0]=(short)f2bf(a.x); r[1]=(short)f2bf(a.y); r[2]=(short)f2bf(a.z); r[3]=(short)f2bf(a.w);
    r[4]=(short)f2bf(b.x); r[5]=(short)f2bf(b.y); r[6]=(short)f2bf(b.z); r[7]=(short)f2bf(b.w);
    return r;
}

__global__ __launch_bounds__(256) void zero_stats(float* stats) {
    stats[threadIdx.x] = 0.0f;   // sum[128] + sumsq[128]
}

// ---------------------------------------------------------------------------
// K1: xT[r][c] (bf16) = x[b][c][p], r = b*HW+p. Register 8x8 micro-transpose.
// Wave covers 64c x 64p; loads 256B-coalesced rows, stores 128B-coalesced rows.
// Block: 4 waves stacked on c -> 256c x 64p. 3136 = 49*64 so block is in one b.
// ---------------------------------------------------------------------------
__global__ __launch_bounds__(256) void transpose_cast(
    const float* __restrict__ x, unsigned short* __restrict__ xT)
{
    const int tid = threadIdx.x;
    const int lane = tid & 63, wv = tid >> 6;
    const int cg = lane & 7, pg = lane >> 3;
    const int blk = blockIdx.x;
    const int b = blk / 49;
    const int pl0 = (blk % 49) * 64 + pg * 8;
    const int c0 = wv * 64 + cg * 8;

    const float* xb = x + ((size_t)b * C_ + c0) * HW_ + pl0;
    float v[8][8];
    #pragma unroll
    for (int k = 0; k < 8; k++) {
        float4 lo = *(const float4*)(xb + (size_t)k * HW_);
        float4 hi = *(const float4*)(xb + (size_t)k * HW_ + 4);
        v[k][0]=lo.x; v[k][1]=lo.y; v[k][2]=lo.z; v[k][3]=lo.w;
        v[k][4]=hi.x; v[k][5]=hi.y; v[k][6]=hi.z; v[k][7]=hi.w;
    }
    const size_t r0 = (size_t)blk * 64 + pg * 8;
    #pragma unroll
    for (int j = 0; j < 8; j++) {
        s16x8 o;
        #pragma unroll
        for (int k = 0; k < 8; k++) o[k] = (short)f2bf(v[k][j]);
        *(s16x8*)(xT + (r0 + j) * 256 + c0) = o;
    }
}

// ---------------------------------------------------------------------------
// K2: t_pm[r][o] = sum_c xT[r][c] * w_reduce[o][c]  (bf16 MFMA 16x16x32)
// Block tile 128o x 128p, 4 waves (2x2) of 64x64. K-chunks of 32.
// LDS rows padded to 40 shorts (80B): frag reads 2-way (free).
// BN sum/sumsq fused into epilogue (no bias: it cancels in BN).
// ---------------------------------------------------------------------------
__global__ __launch_bounds__(256) void reduce_mfma(
    const unsigned short* __restrict__ xT, const float* __restrict__ w_reduce,
    unsigned short* __restrict__ t_pm, float* __restrict__ stats)
{
    __shared__ __align__(16) short as_[128 * 40];
    __shared__ __align__(16) short bs_[128 * 40];

    const int tid = threadIdx.x;
    const int lane = tid & 63, wv = tid >> 6;
    const int q = lane >> 4, i = lane & 15;
    const int mrow = (wv >> 1) * 64, nrow = (wv & 1) * 64;
    const size_t r0 = (size_t)blockIdx.x * 128;

    f32x4 acc[4][4] = {};

    for (int c0 = 0; c0 < C_; c0 += 32) {
        #pragma unroll
        for (int P = 0; P < 2; P++) {
            int idx = P * 256 + tid;
            int row = idx >> 2, k8 = idx & 3;
            const float* srcA = w_reduce + row * C_ + c0 + k8 * 8;
            float4 f0 = *(const float4*)srcA;
            float4 f1 = *(const float4*)(srcA + 4);
            *(s16x8*)&as_[row * 40 + k8 * 8] = pack8(f0, f1);
            const unsigned short* srcB = xT + (r0 + row) * 256 + c0 + k8 * 8;
            *(s16x8*)&bs_[row * 40 + k8 * 8] = *(const s16x8*)srcB;
        }
        __syncthreads();
        s16x8 af[4], bfr[4];
        #pragma unroll
        for (int mt = 0; mt < 4; mt++)
            af[mt] = *(const s16x8*)&as_[(mrow + mt * 16 + i) * 40 + q * 8];
        #pragma unroll
        for (int nt = 0; nt < 4; nt++)
            bfr[nt] = *(const s16x8*)&bs_[(nrow + nt * 16 + i) * 40 + q * 8];
        #pragma unroll
        for (int mt = 0; mt < 4; mt++)
            #pragma unroll
            for (int nt = 0; nt < 4; nt++)
                acc[mt][nt] = __builtin_amdgcn_mfma_f32_16x16x32_bf16(
                    af[mt], bfr[nt], acc[mt][nt], 0, 0, 0);
        __syncthreads();
    }

    // Epilogue: D layout col=lane&15 (=p), row=q*4+reg (=o)
    #pragma unroll
    for (int mt = 0; mt < 4; mt++) {
        #pragma unroll
        for (int nt = 0; nt < 4; nt++) {
            size_t r = r0 + nrow + nt * 16 + i;
            int o0 = mrow + mt * 16 + q * 4;
            s16x4 hv;
            #pragma unroll
            for (int reg = 0; reg < 4; reg++) hv[reg] = (short)f2bf(acc[mt][nt][reg]);
            *(s16x4*)&t_pm[r * CR_ + o0] = hv;
        }
        #pragma unroll
        for (int reg = 0; reg < 4; reg++) {
            float s = 0.f, ss = 0.f;
            #pragma unroll
            for (int nt = 0; nt < 4; nt++) {
                float vv = acc[mt][nt][reg];
                s += vv; ss += vv * vv;
            }
            #pragma unroll
            for (int m = 1; m < 16; m <<= 1) {
                s  += __shfl_xor(s, m);
                ss += __shfl_xor(ss, m);
            }
            if (i == 0) {
                int o = mrow + mt * 16 + q * 4 + reg;
                atomicAdd(&stats[o], s);
                atomicAdd(&stats[CR_ + o], ss);
            }
        }
    }
}

__global__ __launch_bounds__(128) void finalize_stats(
    float* __restrict__ stats, const float* __restrict__ gamma,
    const float* __restrict__ beta)
{
    int i = threadIdx.x;
    float inv_n = 1.0f / (float)NPOS;
    float mu  = stats[i] * inv_n;
    float var = stats[128 + i] * inv_n - mu * mu;
    float sc  = gamma[i] * rsqrtf(var + EPS_);
    stats[256 + i] = sc;
    stats[384 + i] = beta[i] - mu * sc;
}

// ---------------------------------------------------------------------------
// K3: kern[b][o2][p] = sum_o w_span[o2][o] * relu(bn(t_pm[r][o])) + b_span[o2]
// Block tile 144o x 128p; 4 waves split p (144x32 each). BN+ReLU in B staging.
// ---------------------------------------------------------------------------
__global__ __launch_bounds__(256) void span_mfma(
    const unsigned short* __restrict__ t_pm, const float* __restrict__ w_span,
    const float* __restrict__ b_span, const float* __restrict__ stats,
    unsigned short* __restrict__ kern)
{
    __shared__ __align__(16) short as_[144 * 40];
    __shared__ __align__(16) short bs_[128 * 40];
    __shared__ float scs[128], shs[128], bsp[144];

    const int tid = threadIdx.x;
    const int lane = tid & 63, wv = tid >> 6;
    const int q = lane >> 4, i = lane & 15;
    const size_t r0 = (size_t)blockIdx.x * 128;

    if (tid < 128) { scs[tid] = stats[256 + tid]; shs[tid] = stats[384 + tid]; }
    if (tid < 144) bsp[tid] = b_span[tid];
    __syncthreads();

    f32x4 acc[9][2] = {};

    for (int c0 = 0; c0 < CR_; c0 += 32) {
        #pragma unroll
        for (int P = 0; P < 3; P++) {
            int idx = P * 256 + tid;
            if (idx < 576) {
                int row = idx >> 2, k8 = idx & 3;
                const float* srcA = w_span + row * CR_ + c0 + k8 * 8;
                float4 f0 = *(const float4*)srcA;
                float4 f1 = *(const float4*)(srcA + 4);
                *(s16x8*)&as_[row * 40 + k8 * 8] = pack8(f0, f1);
            }
            if (idx < 512) {
                int row = idx >> 2, k8 = idx & 3;
                const unsigned short* srcB = t_pm + (r0 + row) * CR_ + c0 + k8 * 8;
                s16x8 tv = *(const s16x8*)srcB;
                s16x8 ov;
                #pragma unroll
                for (int j = 0; j < 8; j++) {
                    int c = c0 + k8 * 8 + j;
                    float f = bf2f((unsigned short)tv[j]);
                    f = fmaxf(fmaf(f, scs[c], shs[c]), 0.0f);
                    ov[j] = (short)f2bf(f);
                }
                *(s16x8*)&bs_[row * 40 + k8 * 8] = ov;
            }
        }
        __syncthreads();
        s16x8 af[9], bfr[2];
        #pragma unroll
        for (int mt = 0; mt < 9; mt++)
            af[mt] = *(const s16x8*)&as_[(mt * 16 + i) * 40 + q * 8];
        #pragma unroll
        for (int nt = 0; nt < 2; nt++)
            bfr[nt] = *(const s16x8*)&bs_[(wv * 32 + nt * 16 + i) * 40 + q * 8];
        #pragma unroll
        for (int mt = 0; mt < 9; mt++)
            #pragma unroll
            for (int nt = 0; nt < 2; nt++)
                acc[mt][nt] = __builtin_amdgcn_mfma_f32_16x16x32_bf16(
                    af[mt], bfr[nt], acc[mt][nt], 0, 0, 0);
        __syncthreads();
    }

    // Epilogue: kern channel-major [b][144][HW] bf16
    #pragma unroll
    for (int nt = 0; nt < 2; nt++) {
        size_t r = r0 + wv * 32 + nt * 16 + i;
        int b = (int)(r / HW_);
        int p = (int)(r - (size_t)b * HW_);
        #pragma unroll
        for (int mt = 0; mt < 9; mt++) {
            #pragma unroll
            for (int reg = 0; reg < 4; reg++) {
                int o2 = mt * 16 + q * 4 + reg;
                float vv = acc[mt][nt][reg] + bsp[o2];
                kern[((size_t)b * KKG_ + o2) * HW_ + p] = f2bf(vv);
            }
        }
    }
}

// ---------------------------------------------------------------------------
// K4: out[b, g*16+d, p] = sum_kk x[b, g*16+d, p+off(kk)] * kern[b, kk*16+g, p]
// ---------------------------------------------------------------------------
__global__ __launch_bounds__(256) void involution_apply(
    const float* __restrict__ x, const unsigned short* __restrict__ kern,
    float* __restrict__ out)
{
    int gtid = blockIdx.x * 256 + threadIdx.x;
    int pix = gtid % HW_;
    int bg  = gtid / HW_;
    int g = bg & 15;
    int b = bg >> 4;
    int h = pix / W_;
    int w = pix % W_;

    const unsigned short* kb = kern + (size_t)b * KKG_ * HW_ + pix;
    float kv[9];
    #pragma unroll
    for (int kk = 0; kk < 9; kk++)
        kv[kk] = bf2f(kb[(size_t)(kk * G_ + g) * HW_]);

    float acc[16];
    #pragma unroll
    for (int d = 0; d < 16; d++) acc[d] = 0.0f;

    const float* xb = x + (size_t)(b * C_ + g * 16) * HW_;
    #pragma unroll
    for (int di = 0; di < 3; di++) {
        int hh = h + di - 1;
        if (hh < 0 || hh >= W_) continue;
        #pragma unroll
        for (int dj = 0; dj < 3; dj++) {
            int ww = w + dj - 1;
            if (ww < 0 || ww >= W_) continue;
            float kval = kv[di * 3 + dj];
            int off = hh * W_ + ww;
            #pragma unroll
            for (int d = 0; d < 16; d++)
                acc[d] = fmaf(xb[(size_t)d * HW_ + off], kval, acc[d]);
        }
    }
    float* ob = out + (size_t)(b * C_ + g * 16) * HW_ + pix;
    #pragma unroll
    for (int d = 0; d < 16; d++) ob[(size_t)d * HW_] = acc[d];
}

extern "C" void kernel_launch(void* const* d_in, const int* in_sizes, int n_in,
                              void* d_out, int out_size, void* d_ws, size_t ws_size,
                              hipStream_t stream) {
    const float* x        = (const float*)d_in[0];
    const float* w_reduce = (const float*)d_in[1];
    // d_in[2] = b_reduce: unused — a per-channel bias cancels exactly in BN.
    const float* gamma    = (const float*)d_in[3];
    const float* beta     = (const float*)d_in[4];
    const float* w_span   = (const float*)d_in[5];
    const float* b_span   = (const float*)d_in[6];
    float* out = (float*)d_out;

    char* wsb = (char*)d_ws;
    unsigned short* xT   = (unsigned short*)(wsb + XT_OFF_B);
    unsigned short* t_pm = (unsigned short*)(wsb + TPM_OFF_B);
    unsigned short* kern = (unsigned short*)(wsb + KERN_OFF_B);
    float*          stats = (float*)(wsb + STAT_OFF_B);

    transpose_cast<<<NR / 64, 256, 0, stream>>>(x, xT);
    zero_stats<<<1, 256, 0, stream>>>(stats);
    reduce_mfma<<<NR / 128, 256, 0, stream>>>(xT, w_reduce, t_pm, stats);
    finalize_stats<<<1, 128, 0, stream>>>(stats, gamma, beta);
    span_mfma<<<NR / 128, 256, 0, stream>>>(t_pm, w_span, b_span, stats, kern);
    involution_apply<<<(B_ * G_ * HW_) / 256, 256, 0, stream>>>(x, kern, out);
}

// Round 3
// 160.508 us; speedup vs baseline: 1.6126x; 1.6126x over previous
//
#include <hip/hip_runtime.h>

// Problem dims
#define B_   16
#define C_   256
#define HW_  3136      // 56*56
#define W_   56
#define CR_  128
#define KKG_ 144
#define G_   16
#define NPOS (B_*HW_)  // 50176
#define EPS_ 1e-5f
#define NBLK 784       // 16 b * 49 p-tiles of 64

typedef float f32x4 __attribute__((ext_vector_type(4)));
typedef short s16x8 __attribute__((ext_vector_type(8)));
typedef short s16x4 __attribute__((ext_vector_type(4)));

// ws layout (bytes):
//   t2   : [128 o][16 b][3136 p] bf16 = 12,845,056
//   kern : [16 b][144 o2][3136 p] bf16 = 14,450,688
//   gp   : [784 blk][256] f32 (sum[128]|sumsq[128]) = 802,816
//   stats: scale[128]|shift[128] f32 = 1024
//   wbfr : [128][256] bf16 = 65,536
//   wbfs : [144][128] bf16 = 36,864
#define T2_OFF_B    0
#define KERN_OFF_B  12845056
#define GP_OFF_B    27295744
#define STAT_OFF_B  28098560
#define WBFR_OFF_B  28099584
#define WBFS_OFF_B  28165120

__device__ inline unsigned short f2bf(float f) {
    unsigned u = __float_as_uint(f);
    u += 0x7fff + ((u >> 16) & 1);          // RNE
    return (unsigned short)(u >> 16);
}
__device__ inline float bf2f(unsigned short h) {
    return __uint_as_float(((unsigned)h) << 16);
}

// ---------------------------------------------------------------------------
// K0: cast w_reduce (32768) and w_span (18432) to bf16 once.
// ---------------------------------------------------------------------------
__global__ __launch_bounds__(256) void prep_cast(
    const float* __restrict__ w_reduce, const float* __restrict__ w_span,
    unsigned short* __restrict__ wbfr, unsigned short* __restrict__ wbfs)
{
    int idx = blockIdx.x * 256 + threadIdx.x;
    if (idx < 32768) {
        wbfr[idx] = f2bf(w_reduce[idx]);
    } else {
        int k = idx - 32768;
        if (k < 18432) wbfs[k] = f2bf(w_span[k]);
    }
}

// ---------------------------------------------------------------------------
// K1: t2[o][b][p] = sum_c w_reduce[o][c] * x[b][c][p]   (bf16 MFMA 16x16x32)
// Block: 128 o x 64 p (784 blocks, one b each). 4 waves 2x2 over (64o x 32p).
// B staging transposes x in LDS: coalesced float4 along p, b32 c-pair writes.
// BN partials per block -> gp (no atomics).
// ---------------------------------------------------------------------------
__global__ __launch_bounds__(256) void reduce_mfma(
    const float* __restrict__ x, const unsigned short* __restrict__ wbfr,
    unsigned short* __restrict__ t2, float* __restrict__ gp)
{
    __shared__ __align__(16) short as_[128 * 40];   // [o][c-chunk 32] pad->40
    __shared__ __align__(16) short bs_[64 * 40];    // [p][c-chunk 32] pad->40
    __shared__ float redp[128][2], redq[128][2];

    const int tid = threadIdx.x;
    const int lane = tid & 63, wv = tid >> 6;
    const int q = lane >> 4, i = lane & 15;
    const int mrow = (wv >> 1) * 64, nrow = (wv & 1) * 32;
    const int blk = blockIdx.x;
    const int b = blk / 49;
    const int p0 = (blk % 49) * 64;

    const float* xb = x + (size_t)b * C_ * HW_ + p0;

    // staging roles
    const int o_a = tid >> 1, half = tid & 1;       // A: 16 shorts each
    const int cp = tid >> 4, rq = tid & 15;         // B: c-pair x p-quad

    f32x4 acc[4][2] = {};

    for (int c0 = 0; c0 < C_; c0 += 32) {
        // A tile: [128 o][32 c] bf16 copy
        {
            const unsigned short* src = wbfr + o_a * C_ + c0 + half * 16;
            s16x8 w0 = *(const s16x8*)src;
            s16x8 w1 = *(const s16x8*)(src + 8);
            *(s16x8*)&as_[o_a * 40 + half * 16] = w0;
            *(s16x8*)&as_[o_a * 40 + half * 16 + 8] = w1;
        }
        // B tile: transpose x[c][p] -> bs_[p][c], c-pairs packed as b32
        {
            const float* s0 = xb + (size_t)(c0 + 2 * cp) * HW_ + rq * 4;
            float4 va = *(const float4*)s0;
            float4 vb = *(const float4*)(s0 + HW_);
            float a4[4] = {va.x, va.y, va.z, va.w};
            float b4[4] = {vb.x, vb.y, vb.z, vb.w};
            #pragma unroll
            for (int j = 0; j < 4; j++) {
                unsigned pk = (unsigned)f2bf(a4[j]) | ((unsigned)f2bf(b4[j]) << 16);
                *(unsigned*)&bs_[(rq * 4 + j) * 40 + 2 * cp] = pk;
            }
        }
        __syncthreads();
        s16x8 af[4], bfr[2];
        #pragma unroll
        for (int mt = 0; mt < 4; mt++)
            af[mt] = *(const s16x8*)&as_[(mrow + mt * 16 + i) * 40 + q * 8];
        #pragma unroll
        for (int nt = 0; nt < 2; nt++)
            bfr[nt] = *(const s16x8*)&bs_[(nrow + nt * 16 + i) * 40 + q * 8];
        #pragma unroll
        for (int mt = 0; mt < 4; mt++)
            #pragma unroll
            for (int nt = 0; nt < 2; nt++)
                acc[mt][nt] = __builtin_amdgcn_mfma_f32_16x16x32_bf16(
                    af[mt], bfr[nt], acc[mt][nt], 0, 0, 0);
        __syncthreads();
    }

    // Epilogue: D col=i -> p, row=q*4+reg -> o. Store t2[o][b][p] bf16.
    #pragma unroll
    for (int mt = 0; mt < 4; mt++) {
        #pragma unroll
        for (int nt = 0; nt < 2; nt++) {
            #pragma unroll
            for (int reg = 0; reg < 4; reg++) {
                int o = mrow + mt * 16 + q * 4 + reg;
                int p = p0 + nrow + nt * 16 + i;
                t2[((size_t)o * B_ + b) * HW_ + p] = f2bf(acc[mt][nt][reg]);
            }
        }
        // BN partials: sum over nt and i
        #pragma unroll
        for (int reg = 0; reg < 4; reg++) {
            float v0 = acc[mt][0][reg], v1 = acc[mt][1][reg];
            float s = v0 + v1;
            float ss = v0 * v0 + v1 * v1;
            #pragma unroll
            for (int m = 1; m < 16; m <<= 1) {
                s  += __shfl_xor(s, m);
                ss += __shfl_xor(ss, m);
            }
            if (i == 0) {
                int o = mrow + mt * 16 + q * 4 + reg;
                redp[o][wv & 1] = s;
                redq[o][wv & 1] = ss;
            }
        }
    }
    __syncthreads();
    if (tid < 128)
        gp[(size_t)blk * 256 + tid] = redp[tid][0] + redp[tid][1];
    else
        gp[(size_t)blk * 256 + tid] = redq[tid - 128][0] + redq[tid - 128][1];
}

// ---------------------------------------------------------------------------
// K2: sum partials -> scale/shift. One block per channel.
// ---------------------------------------------------------------------------
__global__ __launch_bounds__(256) void bn_finalize(
    const float* __restrict__ gp, const float* __restrict__ gamma,
    const float* __restrict__ beta, float* __restrict__ stats)
{
    const int o = blockIdx.x;
    const int tid = threadIdx.x;
    float s = 0.f, ss = 0.f;
    for (int blk = tid; blk < NBLK; blk += 256) {
        s  += gp[(size_t)blk * 256 + o];
        ss += gp[(size_t)blk * 256 + 128 + o];
    }
    #pragma unroll
    for (int m = 1; m < 64; m <<= 1) {
        s  += __shfl_xor(s, m);
        ss += __shfl_xor(ss, m);
    }
    __shared__ float rs[4], rss[4];
    if ((tid & 63) == 0) { rs[tid >> 6] = s; rss[tid >> 6] = ss; }
    __syncthreads();
    if (tid == 0) {
        s  = rs[0] + rs[1] + rs[2] + rs[3];
        ss = rss[0] + rss[1] + rss[2] + rss[3];
        float inv_n = 1.0f / (float)NPOS;
        float mu = s * inv_n;
        float var = ss * inv_n - mu * mu;
        float sc = gamma[o] * rsqrtf(var + EPS_);
        stats[o] = sc;
        stats[128 + o] = beta[o] - mu * sc;
    }
}

// ---------------------------------------------------------------------------
// K3: kern[b][o2][p] = sum_o w_span[o2][o]*relu(bn(t2[o][b][p])) + b_span[o2]
// Block: 144 o2 x 64 p (784 blocks). 4 waves split p 4-way (144 x 16 each).
// B staging transposes t2 in LDS with BN+ReLU fused (per-channel-pair).
// ---------------------------------------------------------------------------
__global__ __launch_bounds__(256) void span_mfma(
    const unsigned short* __restrict__ t2, const unsigned short* __restrict__ wbfs,
    const float* __restrict__ b_span, const float* __restrict__ stats,
    unsigned short* __restrict__ kern)
{
    __shared__ __align__(16) short as_[144 * 40];
    __shared__ __align__(16) short bs_[64 * 40];
    __shared__ float scs[128], shs[128], bsp[144];

    const int tid = threadIdx.x;
    const int lane = tid & 63, wv = tid >> 6;
    const int q = lane >> 4, i = lane & 15;
    const int blk = blockIdx.x;
    const int b = blk / 49;
    const int p0 = (blk % 49) * 64;

    if (tid < 128) { scs[tid] = stats[tid]; shs[tid] = stats[128 + tid]; }
    if (tid < 144) bsp[tid] = b_span[tid];
    __syncthreads();

    const int op = tid >> 4, seg = tid & 15;   // B staging: o-pair x p-quad

    f32x4 acc[9] = {};

    for (int c0 = 0; c0 < CR_; c0 += 32) {
        // A tile: [144 o2][32 c] bf16 copy (576 x 8-short units, 3 passes)
        #pragma unroll
        for (int P = 0; P < 3; P++) {
            int idx = P * 256 + tid;
            if (idx < 576) {
                int row = idx >> 2, k8 = idx & 3;
                *(s16x8*)&as_[row * 40 + k8 * 8] =
                    *(const s16x8*)&wbfs[row * CR_ + c0 + k8 * 8];
            }
        }
        // B tile: transpose t2[o][p] -> bs_[p][o], BN+ReLU fused
        {
            int cA = c0 + 2 * op;
            const unsigned short* tA = t2 + ((size_t)cA * B_ + b) * HW_ + p0 + seg * 4;
            s16x4 vA = *(const s16x4*)tA;
            s16x4 vB = *(const s16x4*)(tA + (size_t)B_ * HW_);
            float sA = scs[cA], hA = shs[cA];
            float sB = scs[cA + 1], hB = shs[cA + 1];
            #pragma unroll
            for (int j = 0; j < 4; j++) {
                float fa = fmaxf(fmaf(bf2f((unsigned short)vA[j]), sA, hA), 0.0f);
                float fb = fmaxf(fmaf(bf2f((unsigned short)vB[j]), sB, hB), 0.0f);
                unsigned pk = (unsigned)f2bf(fa) | ((unsigned)f2bf(fb) << 16);
                *(unsigned*)&bs_[(seg * 4 + j) * 40 + 2 * op] = pk;
            }
        }
        __syncthreads();
        s16x8 bfrag = *(const s16x8*)&bs_[(wv * 16 + i) * 40 + q * 8];
        #pragma unroll
        for (int mt = 0; mt < 9; mt++) {
            s16x8 af = *(const s16x8*)&as_[(mt * 16 + i) * 40 + q * 8];
            acc[mt] = __builtin_amdgcn_mfma_f32_16x16x32_bf16(af, bfrag, acc[mt], 0, 0, 0);
        }
        __syncthreads();
    }

    // Epilogue: kern[b][o2][p] bf16; col=i -> p, row=q*4+reg -> o2
    const int p = p0 + wv * 16 + i;
    #pragma unroll
    for (int mt = 0; mt < 9; mt++) {
        #pragma unroll
        for (int reg = 0; reg < 4; reg++) {
            int o2 = mt * 16 + q * 4 + reg;
            kern[((size_t)b * KKG_ + o2) * HW_ + p] = f2bf(acc[mt][reg] + bsp[o2]);
        }
    }
}

// ---------------------------------------------------------------------------
// K4: out[b, g*16+d, p] = sum_kk x[b, g*16+d, p+off(kk)] * kern[b, kk*16+g, p]
// ---------------------------------------------------------------------------
__global__ __launch_bounds__(256) void involution_apply(
    const float* __restrict__ x, const unsigned short* __restrict__ kern,
    float* __restrict__ out)
{
    int gtid = blockIdx.x * 256 + threadIdx.x;
    int pix = gtid % HW_;
    int bg  = gtid / HW_;
    int g = bg & 15;
    int b = bg >> 4;
    int h = pix / W_;
    int w = pix % W_;

    const unsigned short* kb = kern + (size_t)b * KKG_ * HW_ + pix;
    float kv[9];
    #pragma unroll
    for (int kk = 0; kk < 9; kk++)
        kv[kk] = bf2f(kb[(size_t)(kk * G_ + g) * HW_]);

    float acc[16];
    #pragma unroll
    for (int d = 0; d < 16; d++) acc[d] = 0.0f;

    const float* xb = x + (size_t)(b * C_ + g * 16) * HW_;
    #pragma unroll
    for (int di = 0; di < 3; di++) {
        int hh = h + di - 1;
        if (hh < 0 || hh >= W_) continue;
        #pragma unroll
        for (int dj = 0; dj < 3; dj++) {
            int ww = w + dj - 1;
            if (ww < 0 || ww >= W_) continue;
            float kval = kv[di * 3 + dj];
            int off = hh * W_ + ww;
            #pragma unroll
            for (int d = 0; d < 16; d++)
                acc[d] = fmaf(xb[(size_t)d * HW_ + off], kval, acc[d]);
        }
    }
    float* ob = out + (size_t)(b * C_ + g * 16) * HW_ + pix;
    #pragma unroll
    for (int d = 0; d < 16; d++) ob[(size_t)d * HW_] = acc[d];
}

extern "C" void kernel_launch(void* const* d_in, const int* in_sizes, int n_in,
                              void* d_out, int out_size, void* d_ws, size_t ws_size,
                              hipStream_t stream) {
    const float* x        = (const float*)d_in[0];
    const float* w_reduce = (const float*)d_in[1];
    // d_in[2] = b_reduce: unused — per-channel bias cancels exactly in BN.
    const float* gamma    = (const float*)d_in[3];
    const float* beta     = (const float*)d_in[4];
    const float* w_span   = (const float*)d_in[5];
    const float* b_span   = (const float*)d_in[6];
    float* out = (float*)d_out;

    char* wsb = (char*)d_ws;
    unsigned short* t2   = (unsigned short*)(wsb + T2_OFF_B);
    unsigned short* kern = (unsigned short*)(wsb + KERN_OFF_B);
    float*          gp    = (float*)(wsb + GP_OFF_B);
    float*          stats = (float*)(wsb + STAT_OFF_B);
    unsigned short* wbfr = (unsigned short*)(wsb + WBFR_OFF_B);
    unsigned short* wbfs = (unsigned short*)(wsb + WBFS_OFF_B);

    prep_cast<<<200, 256, 0, stream>>>(w_reduce, w_span, wbfr, wbfs);
    reduce_mfma<<<NBLK, 256, 0, stream>>>(x, wbfr, t2, gp);
    bn_finalize<<<128, 256, 0, stream>>>(gp, gamma, beta, stats);
    span_mfma<<<NBLK, 256, 0, stream>>>(t2, wbfs, b_span, stats, kern);
    involution_apply<<<(B_ * G_ * HW_) / 256, 256, 0, stream>>>(x, kern, out);
}